// Round 1
// baseline (879.765 us; speedup 1.0000x reference)
//
#include <hip/hip_runtime.h>

typedef unsigned int u32;
typedef unsigned short u16;
typedef float f32x4 __attribute__((ext_vector_type(4)));
typedef short s16x8 __attribute__((ext_vector_type(8)));

static constexpr int kN = 500000;   // points
static constexpr int kC = 10000;    // clusters
static constexpr int kD = 128;      // dims

// ---------- helpers ----------
__device__ __forceinline__ u16 f2bf(float f) {  // fp32 -> bf16 RNE
  u32 b = __float_as_uint(f);
  return (u16)((b + 0x7FFFu + ((b >> 16) & 1u)) >> 16);
}
__device__ __forceinline__ float bf2f(u16 h) {
  return __uint_as_float(((u32)h) << 16);
}
// monotone float<->uint encoding so atomicMax(u32) == float max
__device__ __forceinline__ u32 fenc(float f) {
  int b = __float_as_int(f);
  return (b >= 0) ? ((u32)b | 0x80000000u) : ~((u32)b);
}
__device__ __forceinline__ float fdec(u32 u) {
  int b = (u & 0x80000000u) ? (int)(u & 0x7FFFFFFFu) : (int)(~u);
  return __int_as_float(b);
}

// ---------- W -> bf16 hi/lo split, concat [384][128] (Wv|Wk|Wq) ----------
__global__ void k_wcvt(const float* __restrict__ Wv, const float* __restrict__ Wk,
                       const float* __restrict__ Wq, u16* __restrict__ Wh,
                       u16* __restrict__ Wl) {
  int i = blockIdx.x * blockDim.x + threadIdx.x;
  if (i >= 384 * 128) return;
  int row = i >> 7, col = i & 127;
  float f = (row < 128) ? Wv[row * 128 + col]
          : (row < 256) ? Wk[(row - 128) * 128 + col]
                        : Wq[(row - 256) * 128 + col];
  u16 hb = f2bf(f);
  Wh[i] = hb;
  Wl[i] = f2bf(f - bf2f(hb));
}

// ---------- projections: v,k (bf16 out) + qp -> atomicMax segment max ----------
// block = 256 thr = 4 waves; wave owns 64 points (4 m-subtiles of 16).
// split-bf16 MFMA: acc = xh*Wh + xl*Wh + xh*Wl  (fp32-equivalent)
__global__ __launch_bounds__(256, 2) void k_proj(
    const float* __restrict__ x, const int* __restrict__ cluster,
    const u16* __restrict__ Wh, const u16* __restrict__ Wl,
    const float* __restrict__ bv, const float* __restrict__ bk,
    const float* __restrict__ bq, u16* __restrict__ v_bf, u16* __restrict__ k_bf,
    u32* __restrict__ q_enc) {
  const int lane = threadIdx.x & 63;
  const int wid = threadIdx.x >> 6;
  const int g = lane >> 4;   // 0..3
  const int r = lane & 15;   // 0..15
  const long base_pt = (long)blockIdx.x * 256 + wid * 64;

  // A fragments (x rows), hi/lo bf16.  A[row=l&15][k=8*(l>>4)+j]
  s16x8 ah[4][4], al[4][4];
#pragma unroll
  for (int ms = 0; ms < 4; ++ms) {
    long row = base_pt + ms * 16 + r;
    if (row >= kN) row = kN - 1;  // clamp (stores are predicated)
    const float* xp = x + row * 128;
#pragma unroll
    for (int kk = 0; kk < 4; ++kk) {
      const float4 f0 = *(const float4*)(xp + kk * 32 + g * 8);
      const float4 f1 = *(const float4*)(xp + kk * 32 + g * 8 + 4);
      float f[8] = {f0.x, f0.y, f0.z, f0.w, f1.x, f1.y, f1.z, f1.w};
      s16x8 h, l;
#pragma unroll
      for (int j = 0; j < 8; ++j) {
        u16 hb = f2bf(f[j]);
        h[j] = (short)hb;
        l[j] = (short)f2bf(f[j] - bf2f(hb));
      }
      ah[ms][kk] = h;
      al[ms][kk] = l;
    }
  }

  for (int nt = 0; nt < 24; ++nt) {  // 24 n-tiles of 16 dims (8 per matrix)
    const int mat = nt >> 3;               // 0=v 1=k 2=q
    const int d = (nt & 7) * 16 + r;       // dim within matrix
    const int wrow = nt * 16 + r;          // row in concat W
    s16x8 bh[4], bl[4];
#pragma unroll
    for (int kk = 0; kk < 4; ++kk) {       // B[k=8g+j][col=r] = W[wrow][k]
      bh[kk] = *(const s16x8*)(Wh + wrow * 128 + kk * 32 + g * 8);
      bl[kk] = *(const s16x8*)(Wl + wrow * 128 + kk * 32 + g * 8);
    }
    const float bias = (mat == 0) ? bv[d] : (mat == 1) ? bk[d] : bq[d];
    u16* outp = (mat == 0) ? v_bf : k_bf;
#pragma unroll
    for (int ms = 0; ms < 4; ++ms) {
      f32x4 acc = {0.f, 0.f, 0.f, 0.f};
#pragma unroll
      for (int kk = 0; kk < 4; ++kk) {
        acc = __builtin_amdgcn_mfma_f32_16x16x32_bf16(ah[ms][kk], bh[kk], acc, 0, 0, 0);
        acc = __builtin_amdgcn_mfma_f32_16x16x32_bf16(al[ms][kk], bh[kk], acc, 0, 0, 0);
        acc = __builtin_amdgcn_mfma_f32_16x16x32_bf16(ah[ms][kk], bl[kk], acc, 0, 0, 0);
      }
      const long prow = base_pt + ms * 16 + g * 4;  // D[row=4g+j][col=r]
      if (mat < 2) {
#pragma unroll
        for (int j = 0; j < 4; ++j) {
          long pt = prow + j;
          if (pt < kN) outp[pt * 128 + d] = f2bf(acc[j] + bias);
        }
      } else {
#pragma unroll
        for (int j = 0; j < 4; ++j) {
          long pt = prow + j;
          if (pt < kN) {
            u32 en = fenc(acc[j] + bias);
            atomicMax(q_enc + (long)cluster[pt] * 128 + d, en);
          }
        }
      }
    }
  }
}

// ---------- M[n] = dot(q[c_n], k[n]); m[c] = segment max ----------
__global__ void k_m(const u16* __restrict__ k_bf, const u32* __restrict__ q_enc,
                    const int* __restrict__ cluster, float* __restrict__ M_arr,
                    u32* __restrict__ m_enc) {
  int wid = threadIdx.x >> 6, lane = threadIdx.x & 63;
  int n = blockIdx.x * 4 + wid;  // kN % 4 == 0
  if (n >= kN) return;
  int c = cluster[n];
  u32 kb = *(const u32*)(k_bf + (long)n * 128 + lane * 2);
  uint2 qe = *(const uint2*)(q_enc + (long)c * 128 + lane * 2);
  float k0 = __uint_as_float((kb & 0xFFFFu) << 16);
  float k1 = __uint_as_float(kb & 0xFFFF0000u);
  float p = k0 * fdec(qe.x) + k1 * fdec(qe.y);
#pragma unroll
  for (int off = 32; off; off >>= 1) p += __shfl_xor(p, off, 64);
  if (lane == 0) {
    M_arr[n] = p;
    atomicMax(m_enc + c, fenc(p));
  }
}

// ---------- e = exp(M - m[c]); s[c] += e ----------
__global__ void k_expsum(const float* __restrict__ M_arr, const u32* __restrict__ m_enc,
                         const int* __restrict__ cluster, float* __restrict__ e_arr,
                         float* __restrict__ s_sum) {
  int n = blockIdx.x * blockDim.x + threadIdx.x;
  if (n >= kN) return;
  int c = cluster[n];
  float e = __expf(M_arr[n] - fdec(m_enc[c]));
  e_arr[n] = e;
  atomicAdd(s_sum + c, e);
}

// ---------- BN stats: sum(y), sum(y^2) per dim; also a = e/s stored ----------
__global__ void k_bnstats(const u16* __restrict__ v_bf, const float* __restrict__ e_arr,
                          const float* __restrict__ s_sum, const int* __restrict__ cluster,
                          float* __restrict__ a_arr, double* __restrict__ bn_mu,
                          double* __restrict__ bn_m2) {
  __shared__ float a_sh[512];
  const int tid = threadIdx.x;  // 128 threads
  const long p0 = (long)blockIdx.x * 512;
  for (int i = tid; i < 512; i += 128) {
    long n = p0 + i;
    float a = 0.f;
    if (n < kN) {
      a = e_arr[n] / s_sum[cluster[n]];
      a_arr[n] = a;
    }
    a_sh[i] = a;
  }
  __syncthreads();
  const int d = tid;
  long rem = kN - p0;
  int cnt = rem < 512 ? (int)rem : 512;
  float smu = 0.f, sm2 = 0.f;
#pragma unroll 4
  for (int p = 0; p < cnt; ++p) {
    float vv = bf2f(v_bf[(p0 + p) * 128 + d]);
    float y = a_sh[p] * vv;
    smu += y;
    sm2 += y * y;
  }
  atomicAdd(bn_mu + d, (double)smu);
  atomicAdd(bn_m2 + d, (double)sm2);
}

// ---------- finalize BN: scale/shift per dim ----------
__global__ void k_bnfinal(const double* __restrict__ bn_mu, const double* __restrict__ bn_m2,
                          const float* __restrict__ gamma, const float* __restrict__ beta,
                          float* __restrict__ scale, float* __restrict__ shift) {
  int d = threadIdx.x;  // 128
  double mu = bn_mu[d] / (double)kN;
  double var = bn_m2[d] / (double)kN - mu * mu;
  float inv = rsqrtf((float)var + 1e-5f);
  float sc = gamma[d] * inv;
  scale[d] = sc;
  shift[d] = beta[d] - (float)mu * sc;
}

// ---------- out = leakyrelu((a*v)*scale + shift) ----------
__global__ void k_out(const u16* __restrict__ v_bf, const float* __restrict__ a_arr,
                      const float* __restrict__ scale, const float* __restrict__ shift,
                      float* __restrict__ out) {
  long i = (long)blockIdx.x * blockDim.x + threadIdx.x;  // kN*16 slots of 8 dims
  if (i >= (long)kN * 16) return;
  long n = i >> 4;
  int d0 = (int)(i & 15) * 8;
  float a = a_arr[n];
  uint4 raw = *(const uint4*)(v_bf + n * 128 + d0);
  float4 sc0 = *(const float4*)(scale + d0);
  float4 sc1 = *(const float4*)(scale + d0 + 4);
  float4 sh0 = *(const float4*)(shift + d0);
  float4 sh1 = *(const float4*)(shift + d0 + 4);
  u32 w[4] = {raw.x, raw.y, raw.z, raw.w};
  float vv[8];
#pragma unroll
  for (int q = 0; q < 4; ++q) {
    vv[2 * q] = __uint_as_float((w[q] & 0xFFFFu) << 16);
    vv[2 * q + 1] = __uint_as_float(w[q] & 0xFFFF0000u);
  }
  float sc[8] = {sc0.x, sc0.y, sc0.z, sc0.w, sc1.x, sc1.y, sc1.z, sc1.w};
  float sh[8] = {sh0.x, sh0.y, sh0.z, sh0.w, sh1.x, sh1.y, sh1.z, sh1.w};
  float o[8];
#pragma unroll
  for (int q = 0; q < 8; ++q) {
    float y = fmaf(a * vv[q], sc[q], sh[q]);
    o[q] = (y >= 0.f) ? y : 0.2f * y;
  }
  float4 o0 = {o[0], o[1], o[2], o[3]};
  float4 o1 = {o[4], o[5], o[6], o[7]};
  *(float4*)(out + n * 128 + d0) = o0;
  *(float4*)(out + n * 128 + d0 + 4) = o1;
}

extern "C" void kernel_launch(void* const* d_in, const int* in_sizes, int n_in,
                              void* d_out, int out_size, void* d_ws, size_t ws_size,
                              hipStream_t stream) {
  const float* x = (const float*)d_in[0];
  const int* cluster = (const int*)d_in[1];
  const float* Wv = (const float*)d_in[2];
  const float* bv = (const float*)d_in[3];
  const float* Wk = (const float*)d_in[4];
  const float* bk = (const float*)d_in[5];
  const float* Wq = (const float*)d_in[6];
  const float* bq = (const float*)d_in[7];
  const float* gamma = (const float*)d_in[8];
  const float* beta = (const float*)d_in[9];
  float* out = (float*)d_out;

  char* ws = (char*)d_ws;
  // layout (bytes)
  u16* Wh = (u16*)(ws + 0);                  //    98,304
  u16* Wl = (u16*)(ws + 98304);              //    98,304
  u32* q_enc = (u32*)(ws + 196608);          // 5,120,000
  u32* m_enc = (u32*)(ws + 5316608);         //    40,000
  float* s_sum = (float*)(ws + 5356608);     //    40,000
  double* bn_mu = (double*)(ws + 5396608);   //     1,024
  double* bn_m2 = (double*)(ws + 5397632);   //     1,024
  float* scale = (float*)(ws + 5398656);     //       512
  float* shift = (float*)(ws + 5399168);     //       512
  float* M_arr = (float*)(ws + 5399680);     // 2,000,000
  float* e_arr = (float*)(ws + 7399680);     // 2,000,000
  float* a_arr = (float*)(ws + 9399680);     // 2,000,000
  u16* v_bf = (u16*)(ws + 11399680);         // 128,000,000
  u16* k_bf = (u16*)(ws + 139399680);        // 128,000,000 -> total 267,399,680

  // zero accumulators (q_enc..bn_m2); encoded 0 == "below -inf" for max
  hipMemsetAsync(ws + 196608, 0, 5398656 - 196608, stream);

  k_wcvt<<<192, 256, 0, stream>>>(Wv, Wk, Wq, Wh, Wl);
  k_proj<<<(kN + 255) / 256, 256, 0, stream>>>(x, cluster, Wh, Wl, bv, bk, bq,
                                               v_bf, k_bf, q_enc);
  k_m<<<kN / 4, 256, 0, stream>>>(k_bf, q_enc, cluster, M_arr, m_enc);
  k_expsum<<<(kN + 255) / 256, 256, 0, stream>>>(M_arr, m_enc, cluster, e_arr, s_sum);
  k_bnstats<<<(kN + 511) / 512, 128, 0, stream>>>(v_bf, e_arr, s_sum, cluster, a_arr,
                                                  bn_mu, bn_m2);
  k_bnfinal<<<1, 128, 0, stream>>>(bn_mu, bn_m2, gamma, beta, scale, shift);
  k_out<<<(int)(((long)kN * 16 + 255) / 256), 256, 0, stream>>>(v_bf, a_arr, scale,
                                                                shift, out);
}